// Round 2
// baseline (186.204 us; speedup 1.0000x reference)
//
#include <hip/hip_runtime.h>
#include <hip/hip_bf16.h>
#include <stdint.h>

// B=2, N=2048, D=1024, H=8, DH=128. Inputs fp32, OUTPUT fp32.
// qkv col (reference) = kk*1024 + dd*8 + hh (head innermost). No softmax =>
//   out = sum_h Q_h (K_h^T V_h) Wo_h^T + b_o.
// v3 pipeline (6 kernels):
//   conv_all: x->bf16; w_qkv rows PERMUTED so gemm1 emits cols [kk][hh][dd];
//             w_o->bf16; b_qkv permuted (fp32).
//   gemm1:    256^2-tile 8-phase schedule (T2 swizzle + T3/T4 counted vmcnt +
//             T5 setprio). qkv[4096][3072] bf16 (+bias).
//   kv_part:  Mpart[bh][ch][e][d] += K[n][e]*V[n][d] (fp32, vector ALU).
//   reduce_m: M[bh][e][d] bf16 = sum_ch Mpart.
//   wprime:   Wt_b[o][h*128+e] = sum_d wo[o][h*128+d]*M[bh][e][d]  (MFMA, K=128)
//   gemm2:    out[bn][o] = sum_he qkv[bn][he] * Wt_b[o][he] + b_o  (fp32 out)
// ws map (40 MB):
//   [0,8M)    xb      -> Mb [0,0.5M) + Wt [1M,5M)   (after gemm1)
//   [8,14M)   wqkvb   (dead after gemm1)
//   [14,16M)  wob     (live through wprime)
//   [16,40M)  qkv     (live through gemm2)
// d_out (16MB): bqp [0,12K) during gemm1; Mpart [0,16M) after gemm1;
//   overwritten by gemm2's final output.

typedef __bf16 bf16_t;
typedef __bf16 bf16x4 __attribute__((ext_vector_type(4)));
typedef __bf16 bf16x8 __attribute__((ext_vector_type(8)));
typedef float  fx4    __attribute__((ext_vector_type(4)));
typedef unsigned short u16;
typedef u16 u16x8 __attribute__((ext_vector_type(8)));

typedef const void __attribute__((address_space(1)))* gas_ptr;
typedef void __attribute__((address_space(3)))*       las_ptr;

__device__ __forceinline__ void gl_lds16(const void* g, void* l) {
  __builtin_amdgcn_global_load_lds((gas_ptr)g, (las_ptr)l, 16, 0, 0);
}

// ---------------------------------------------------------------------------
__global__ __launch_bounds__(256) void beacon_kernel(float* out, float val, int n)
{
  const int i = blockIdx.x * 256 + threadIdx.x;
  if (i < n) out[i] = val;
}

// ---------------------------------------------------------------------------
__global__ __launch_bounds__(256) void conv_all_kernel(
    const float* __restrict__ x, const float* __restrict__ wq,
    const float* __restrict__ wo, const float* __restrict__ bq,
    bf16_t* __restrict__ xb, bf16_t* __restrict__ wqkvb,
    bf16_t* __restrict__ wob, float* __restrict__ bqp)
{
  const int i = blockIdx.x * 256 + threadIdx.x;   // < 2097920
  if (i < 2097152) {
    const float* src; bf16_t* dst; int soff, doff;
    if (i < 1048576) { src = x; dst = xb; soff = i; doff = i; }
    else if (i < 1835008) {
      const int j  = i - 1048576;
      const int rp = j >> 8, g = j & 255;       // dst row c' (0..3071), float4 group
      const int kk = rp >> 10, rem = rp & 1023;
      const int hh = rem >> 7,  dd = rem & 127;
      const int r  = kk * 1024 + dd * 8 + hh;   // src row c
      src = wq; dst = wqkvb; soff = r * 256 + g; doff = j;
    } else {
      const int j = i - 1835008;
      src = wo; dst = wob; soff = j; doff = j;
    }
    const float4 v = ((const float4*)src)[soff];
    bf16x4 o;
    o[0] = (bf16_t)v.x; o[1] = (bf16_t)v.y; o[2] = (bf16_t)v.z; o[3] = (bf16_t)v.w;
    ((bf16x4*)dst)[doff] = o;
  } else if (i < 2097920) {
    const int j = i - 2097152;                  // 0..767
    float4 v;
    float* pv = (float*)&v;
#pragma unroll
    for (int q = 0; q < 4; ++q) {
      const int cp = j * 4 + q;
      const int kk = cp >> 10, rem = cp & 1023;
      const int hh = rem >> 7,  dd = rem & 127;
      pv[q] = bq[kk * 1024 + dd * 8 + hh];
    }
    ((float4*)bqp)[j] = v;
  }
}

// ---------------------------------------------------------------------------
// gemm1: 256x256-tile, 8-wave (2Mx4N), BK=64, double-buffered LDS (128 KiB),
// st_16x32 XOR swizzle, counted vmcnt, setprio around MFMA cluster.
// C[4096,3072] = A[4096,1024] @ Bt[3072,1024]^T + bias (bf16 out, ldc=3072).
// Quadrant phases per K-tile: (mh,nh) = (0,0),(0,1),(1,0),(1,1).
// Half death: A0 after ph2, B0 after ph3, A1/B1 after ph4.
// Stage per phase: ph1 A1(t+1) [other slot], ph2 B1(t+1), ph3 A0(t+2) [cur],
// ph4 B0(t+2). Boundary: vmcnt(4) (leaves A0/B0(t+2) in flight), vmcnt(0) tail.

__device__ __forceinline__ void stage_pair(short* dstbase, int tt,
                                           const bf16_t* g0, const bf16_t* g1) {
  gl_lds16(g0, dstbase + tt * 8);
  gl_lds16(g1, dstbase + 4096 + tt * 8);
}

template<int MH, int NH>
__device__ __forceinline__ void phase_op(
    const short* la, const short* lb,
    int wm, int wn, int lrow, int kb0, int kb1,
    fx4 (&acc)[2][2][4][2],
    bool do_stage, short* sdst, const bf16_t* g0, const bf16_t* g1, int tt)
{
  bf16x8 af[4][2];
  bf16x8 bfr[2][2];
#pragma unroll
  for (int fi = 0; fi < 4; ++fi) {
    const int Lr = MH * 128 + wm * 64 + fi * 16 + lrow;
    af[fi][0] = *(const bf16x8*)&la[Lr * 64 + (kb0 >> 1)];
    af[fi][1] = *(const bf16x8*)&la[Lr * 64 + (kb1 >> 1)];
  }
#pragma unroll
  for (int fj = 0; fj < 2; ++fj) {
    const int Lr = NH * 128 + wn * 32 + fj * 16 + lrow;
    bfr[fj][0] = *(const bf16x8*)&lb[Lr * 64 + (kb0 >> 1)];
    bfr[fj][1] = *(const bf16x8*)&lb[Lr * 64 + (kb1 >> 1)];
  }
  if (do_stage) {
    gl_lds16(g0, sdst + tt * 8);
    gl_lds16(g1, sdst + 4096 + tt * 8);
  }
  asm volatile("s_barrier" ::: "memory");
  __builtin_amdgcn_s_setprio(1);
#pragma unroll
  for (int fi = 0; fi < 4; ++fi)
#pragma unroll
    for (int fj = 0; fj < 2; ++fj) {
      acc[MH][NH][fi][fj] = __builtin_amdgcn_mfma_f32_16x16x32_bf16(
          af[fi][0], bfr[fj][0], acc[MH][NH][fi][fj], 0, 0, 0);
      acc[MH][NH][fi][fj] = __builtin_amdgcn_mfma_f32_16x16x32_bf16(
          af[fi][1], bfr[fj][1], acc[MH][NH][fi][fj], 0, 0, 0);
    }
  __builtin_amdgcn_s_setprio(0);
  asm volatile("s_barrier" ::: "memory");
}

__global__ __launch_bounds__(512, 2) void gemm1_256_kernel(
    const bf16_t* __restrict__ A, const bf16_t* __restrict__ Bt,
    const float* __restrict__ bias, bf16_t* __restrict__ outb)
{
  __shared__ __align__(16) short LA[2][16384];   // [slot][half(128 rows)][64 k]
  __shared__ __align__(16) short LB[2][16384];

  const int tt   = threadIdx.x;          // 0..511
  const int lane = tt & 63;
  const int w    = tt >> 6;              // 0..7
  const int wm   = w >> 2;               // 0..1 (rows, 128 each)
  const int wn   = w & 3;                // 0..3 (cols, 64 each)
  const int lrow = lane & 15;
  const int kq16 = (lane >> 4) << 4;     // k byte offset within 32-k slice
  const int xm   = (lane & 4) << 3;      // st_16x32 swizzle mask (bit5 per bit9=row&4)
  const int kb0  = kq16 ^ xm;
  const int kb1  = (64 + kq16) ^ xm;
  const int row0 = blockIdx.y * 256;
  const int col0 = blockIdx.x * 256;

  // Per-thread stage sources (pre-swizzled global addresses; rule #21).
  // LDS linear byte X holds linear element X^(((X>>9)&1)<<5).
  int offL[2];
  offL[0] = (tt * 16) ^ ((tt & 32) ? 32 : 0);
  offL[1] = ((512 + tt) * 16) ^ ((tt & 32) ? 32 : 0);
  const bf16_t* pA[2][2];   // [half][L]
  const bf16_t* pB[2][2];
#pragma unroll
  for (int L = 0; L < 2; ++L) {
    const int rl = offL[L] >> 7;
    const int ke = (offL[L] & 127) >> 1;
    const int wmS = rl >> 6, rA = rl & 63;
    const int wnS = rl >> 5, rB = rl & 31;
#pragma unroll
    for (int h = 0; h < 2; ++h) {
      pA[h][L] = A  + (size_t)(row0 + wmS * 128 + h * 64 + rA) * 1024 + ke;
      pB[h][L] = Bt + (size_t)(col0 + wnS * 64  + h * 32 + rB) * 1024 + ke;
    }
  }

  fx4 acc[2][2][4][2] = {};

  // Prologue: tile0 full + A0/B0 of tile1 (6 half-tiles, 12 loads/thread).
  stage_pair(&LA[0][0],    tt, pA[0][0],      pA[0][1]);       // A0(0)
  stage_pair(&LB[0][0],    tt, pB[0][0],      pB[0][1]);       // B0(0)
  stage_pair(&LA[0][8192], tt, pA[1][0],      pA[1][1]);       // A1(0)
  stage_pair(&LB[0][8192], tt, pB[1][0],      pB[1][1]);       // B1(0)
  stage_pair(&LA[1][0],    tt, pA[0][0] + 64, pA[0][1] + 64);  // A0(1)
  stage_pair(&LB[1][0],    tt, pB[0][0] + 64, pB[0][1] + 64);  // B0(1)
  asm volatile("s_waitcnt vmcnt(4)" ::: "memory");  // tile0's 4 halves landed
  asm volatile("s_barrier" ::: "memory");

  for (int t = 0; t < 16; ++t) {
    short* la  = &LA[t & 1][0];
    short* lb  = &LB[t & 1][0];
    short* laN = &LA[(t + 1) & 1][0];
    short* lbN = &LB[(t + 1) & 1][0];
    const bool s1 = (t + 1 < 16);
    const bool s2 = (t + 2 < 16);
    const int k1 = (t + 1) * 64;
    const int k2 = (t + 2) * 64;

    phase_op<0, 0>(la, lb, wm, wn, lrow, kb0, kb1, acc,
                   s1, laN + 8192, pA[1][0] + k1, pA[1][1] + k1, tt); // A1(t+1)
    phase_op<0, 1>(la, lb, wm, wn, lrow, kb0, kb1, acc,
                   s1, lbN + 8192, pB[1][0] + k1, pB[1][1] + k1, tt); // B1(t+1)
    phase_op<1, 0>(la, lb, wm, wn, lrow, kb0, kb1, acc,
                   s2, la,         pA[0][0] + k2, pA[0][1] + k2, tt); // A0(t+2)
    phase_op<1, 1>(la, lb, wm, wn, lrow, kb0, kb1, acc,
                   s2, lb,         pB[0][0] + k2, pB[0][1] + k2, tt); // B0(t+2)

    if (t < 15) {
      if (s2) asm volatile("s_waitcnt vmcnt(4)" ::: "memory"); // keep 2 halves in flight
      else    asm volatile("s_waitcnt vmcnt(0)" ::: "memory"); // tail drain
      asm volatile("s_barrier" ::: "memory");
    }
  }

  const int q4 = (lane >> 4) << 2;
#pragma unroll
  for (int mh = 0; mh < 2; ++mh)
#pragma unroll
    for (int nh = 0; nh < 2; ++nh)
#pragma unroll
      for (int fj = 0; fj < 2; ++fj) {
        const int col = col0 + wn * 64 + nh * 32 + fj * 16 + lrow;
        const float bv = bias[col];
#pragma unroll
        for (int fi = 0; fi < 4; ++fi) {
#pragma unroll
          for (int r = 0; r < 4; ++r) {
            const int row = row0 + wm * 128 + mh * 64 + fi * 16 + q4 + r;
            outb[(size_t)row * 3072 + col] = (bf16_t)(acc[mh][nh][fi][fj][r] + bv);
          }
        }
      }
}

// ---------------------------------------------------------------------------
// MFMA GEMM (m97 structure), K=1024 — used for gemm2 only.
__global__ __launch_bounds__(256) void mfma_gemm_kernel(
    const bf16_t* __restrict__ A, int lda,
    const bf16_t* __restrict__ Bt0, int ldb, size_t bt_bstride,
    const float* __restrict__ bias,
    bf16_t* __restrict__ outb, float* __restrict__ outf, int ldc, int mode)
{
  __shared__ __align__(16) short As[128*32];
  __shared__ __align__(16) short Bs[128*32];
  const int t    = threadIdx.x;
  const int lane = t & 63;
  const int w    = t >> 6;
  const int wr   = (w >> 1) << 6;
  const int wc   = (w & 1) << 6;
  const int lrow = lane & 15;
  const int kq   = (lane >> 4) << 3;
  const int row0 = blockIdx.y * 128;
  const int col0 = blockIdx.x * 128;
  const bf16_t* Bt = Bt0 + (row0 >= 2048 ? bt_bstride : (size_t)0);

  const int i0 = t, i1 = t + 256;
  const bf16_t* a0 = A  + (size_t)(row0 + (i0 >> 2)) * lda + ((i0 & 3) << 3);
  const bf16_t* a1 = A  + (size_t)(row0 + (i1 >> 2)) * lda + ((i1 & 3) << 3);
  const bf16_t* b0 = Bt + (size_t)(col0 + (i0 >> 2)) * ldb + ((i0 & 3) << 3);
  const bf16_t* b1 = Bt + (size_t)(col0 + (i1 >> 2)) * ldb + ((i1 & 3) << 3);
  short* sa0 = &As[i0 * 8]; short* sa1 = &As[i1 * 8];
  short* sb0 = &Bs[i0 * 8]; short* sb1 = &Bs[i1 * 8];

  fx4 acc[4][4] = {};

  for (int k0 = 0; k0 < 1024; k0 += 32) {
    gl_lds16(a0 + k0, sa0);
    gl_lds16(a1 + k0, sa1);
    gl_lds16(b0 + k0, sb0);
    gl_lds16(b1 + k0, sb1);
    __syncthreads();
    bf16x8 af[4], bfr[4];
#pragma unroll
    for (int i = 0; i < 4; ++i)
      af[i] = *(const bf16x8*)&As[(wr + i*16 + lrow)*32 + kq];
#pragma unroll
    for (int j = 0; j < 4; ++j)
      bfr[j] = *(const bf16x8*)&Bs[(wc + j*16 + lrow)*32 + kq];
#pragma unroll
    for (int i = 0; i < 4; ++i)
#pragma unroll
      for (int j = 0; j < 4; ++j)
        acc[i][j] = __builtin_amdgcn_mfma_f32_16x16x32_bf16(af[i], bfr[j], acc[i][j], 0, 0, 0);
    __syncthreads();
  }

#pragma unroll
  for (int j = 0; j < 4; ++j) {
    const int col = col0 + wc + j*16 + lrow;
    const float bv = bias[col];
#pragma unroll
    for (int i = 0; i < 4; ++i) {
#pragma unroll
      for (int r = 0; r < 4; ++r) {
        const int row = row0 + wr + i*16 + ((lane >> 4) << 2) + r;
        const float v = acc[i][j][r] + bv;
        if (mode == 0) outb[(size_t)row * ldc + col] = (bf16_t)v;
        else           outf[(size_t)row * ldc + col] = v;
      }
    }
  }
}

// ---------------------------------------------------------------------------
__global__ __launch_bounds__(256) void kv_part(
    const bf16_t* __restrict__ qkv, float* __restrict__ Mpart)
{
  __shared__ float Ksf[64][128];   // 32 KB
  __shared__ float Vsf[64][64];    // 16 KB
  const int t = threadIdx.x;
  const int ch = blockIdx.x >> 1, dh = blockIdx.x & 1, bh = blockIdx.y;
  const int b = bh >> 3, h = bh & 7;
  const bf16_t* Kg = qkv + (size_t)(b * 2048) * 3072 + 1024 + h * 128;
  const bf16_t* Vg = qkv + (size_t)(b * 2048) * 3072 + 2048 + h * 128 + dh * 64;
  const int e0 = (t >> 4) * 8, d0 = (t & 15) * 4;
  float acc[8][4] = {};

  for (int sub = 0; sub < 2; ++sub) {
    const int n0 = ch * 128 + sub * 64;
#pragma unroll
    for (int p = 0; p < 4; ++p) {           // K: 1024 groups of 8
      const int idx = t + p * 256;
      const int r = idx >> 4, c = (idx & 15) * 8;
      const bf16x8 k8 = *(const bf16x8*)(Kg + (size_t)(n0 + r) * 3072 + c);
      float4 f0 = { (float)k8[0], (float)k8[1], (float)k8[2], (float)k8[3] };
      float4 f1 = { (float)k8[4], (float)k8[5], (float)k8[6], (float)k8[7] };
      *(float4*)&Ksf[r][c]     = f0;
      *(float4*)&Ksf[r][c + 4] = f1;
    }
#pragma unroll
    for (int p = 0; p < 2; ++p) {           // V: 512 groups of 8
      const int idx = t + p * 256;
      const int r = idx >> 3, c = (idx & 7) * 8;
      const bf16x8 v8 = *(const bf16x8*)(Vg + (size_t)(n0 + r) * 3072 + c);
      float4 f0 = { (float)v8[0], (float)v8[1], (float)v8[2], (float)v8[3] };
      float4 f1 = { (float)v8[4], (float)v8[5], (float)v8[6], (float)v8[7] };
      *(float4*)&Vsf[r][c]     = f0;
      *(float4*)&Vsf[r][c + 4] = f1;
    }
    __syncthreads();
    for (int n = 0; n < 64; ++n) {
      const float4 ka = *(const float4*)&Ksf[n][e0];
      const float4 kb = *(const float4*)&Ksf[n][e0 + 4];
      const float4 vv = *(const float4*)&Vsf[n][d0];
      const float kf[8] = { ka.x, ka.y, ka.z, ka.w, kb.x, kb.y, kb.z, kb.w };
      const float vf[4] = { vv.x, vv.y, vv.z, vv.w };
#pragma unroll
      for (int i = 0; i < 8; ++i)
#pragma unroll
        for (int j = 0; j < 4; ++j) acc[i][j] += kf[i] * vf[j];
    }
    __syncthreads();
  }

  float* op = Mpart + ((size_t)(bh * 16 + ch) << 14) + dh * 64;
#pragma unroll
  for (int i = 0; i < 8; ++i)
    *(float4*)&op[(e0 + i) * 128 + d0] = *(const float4*)&acc[i][0];
}

// ---------------------------------------------------------------------------
__global__ __launch_bounds__(256) void reduce_m(
    const float* __restrict__ Mpart, bf16_t* __restrict__ Mb)
{
  const int t = threadIdx.x, bh = blockIdx.y;
  const int task = blockIdx.x * 256 + t;    // 0..2047
  const int e = task >> 4, doct = task & 15;
  const float* base = Mpart + ((size_t)(bh * 16) << 14) + e * 128 + doct * 8;
  float s[8] = {};
#pragma unroll
  for (int ch = 0; ch < 16; ++ch) {
    const float* p = base + ((size_t)ch << 14);
    const float4 v0 = *(const float4*)p;
    const float4 v1 = *(const float4*)(p + 4);
    s[0] += v0.x; s[1] += v0.y; s[2] += v0.z; s[3] += v0.w;
    s[4] += v1.x; s[5] += v1.y; s[6] += v1.z; s[7] += v1.w;
  }
  u16x8 wv;
#pragma unroll
  for (int j = 0; j < 8; ++j) { bf16_t bb = (bf16_t)s[j]; wv[j] = *(u16*)&bb; }
  *(u16x8*)(Mb + (size_t)bh * 16384 + e * 128 + doct * 8) = wv;
}

// ---------------------------------------------------------------------------
__global__ __launch_bounds__(256) void wprime_kernel(
    const bf16_t* __restrict__ wob, const bf16_t* __restrict__ Mb,
    bf16_t* __restrict__ Wt)
{
  __shared__ __align__(16) short As[128*32];
  __shared__ __align__(16) short Bs[128*32];
  const int t    = threadIdx.x;
  const int lane = t & 63;
  const int w    = t >> 6;
  const int wr   = (w >> 1) << 6;
  const int wc   = (w & 1) << 6;
  const int lrow = lane & 15;
  const int kq   = (lane >> 4) << 3;
  const int o0   = blockIdx.x * 128;
  const int bh   = blockIdx.y, b = bh >> 3, h = bh & 7;
  const bf16_t* A  = wob + (size_t)o0 * 1024 + h * 128;
  const bf16_t* Bt = Mb + (size_t)bh * 16384;

  const int i0 = t, i1 = t + 256;
  const bf16_t* a0 = A  + (size_t)(i0 >> 2) * 1024 + ((i0 & 3) << 3);
  const bf16_t* a1 = A  + (size_t)(i1 >> 2) * 1024 + ((i1 & 3) << 3);
  const bf16_t* b0 = Bt + (size_t)(i0 >> 2) * 128  + ((i0 & 3) << 3);
  const bf16_t* b1 = Bt + (size_t)(i1 >> 2) * 128  + ((i1 & 3) << 3);
  short* sa0 = &As[i0 * 8]; short* sa1 = &As[i1 * 8];
  short* sb0 = &Bs[i0 * 8]; short* sb1 = &Bs[i1 * 8];

  fx4 acc[4][4] = {};

  for (int k0 = 0; k0 < 128; k0 += 32) {
    gl_lds16(a0 + k0, sa0);
    gl_lds16(a1 + k0, sa1);
    gl_lds16(b0 + k0, sb0);
    gl_lds16(b1 + k0, sb1);
    __syncthreads();
    bf16x8 af[4], bfr[4];
#pragma unroll
    for (int i = 0; i < 4; ++i)
      af[i] = *(const bf16x8*)&As[(wr + i*16 + lrow)*32 + kq];
#pragma unroll
    for (int j = 0; j < 4; ++j)
      bfr[j] = *(const bf16x8*)&Bs[(wc + j*16 + lrow)*32 + kq];
#pragma unroll
    for (int i = 0; i < 4; ++i)
#pragma unroll
      for (int j = 0; j < 4; ++j)
        acc[i][j] = __builtin_amdgcn_mfma_f32_16x16x32_bf16(af[i], bfr[j], acc[i][j], 0, 0, 0);
    __syncthreads();
  }

  bf16_t* obase = Wt + (size_t)b * 1048576 + h * 128;
#pragma unroll
  for (int j = 0; j < 4; ++j) {
    const int col = wc + j*16 + lrow;                 // e 0..127
#pragma unroll
    for (int i = 0; i < 4; ++i) {
#pragma unroll
      for (int r = 0; r < 4; ++r) {
        const int row = o0 + wr + i*16 + ((lane >> 4) << 2) + r;   // o
        obase[(size_t)row * 1024 + col] = (bf16_t)acc[i][j][r];
      }
    }
  }
}

// ---------------------------------------------------------------------------
extern "C" void kernel_launch(void* const* d_in, const int* in_sizes, int n_in,
                              void* d_out, int out_size, void* d_ws, size_t ws_size,
                              hipStream_t stream) {
  float* out = (float*)d_out;
  dim3 blk(256);

  int ix = -1, iwq = -1, ibq = -1, iwo = -1, ibo = -1;
  if (n_in == 5) {
    for (int i = 0; i < 5; ++i) {
      switch (in_sizes[i]) {
        case 4194304: ix  = i; break;
        case 3145728: iwq = i; break;
        case 3072:    ibq = i; break;
        case 1048576: iwo = i; break;
        case 1024:    ibo = i; break;
        default: break;
      }
    }
  }
  if (ix < 0 || iwq < 0 || ibq < 0 || iwo < 0 || ibo < 0) {
    beacon_kernel<<<dim3((out_size + 255) / 256), blk, 0, stream>>>(out, 50000.0f, out_size);
    return;
  }
  const size_t NEEDED = (size_t)40 * 1048576;
  if (ws_size < NEEDED) {
    beacon_kernel<<<dim3((out_size + 255) / 256), blk, 0, stream>>>(out, 30000.0f, out_size);
    return;
  }

  char* ws = (char*)d_ws;
  bf16_t* xb     = (bf16_t*)(ws);                          // [0,8M)
  bf16_t* wqkvb  = (bf16_t*)(ws + (size_t)8  * 1048576);   // [8,14M)
  bf16_t* wob    = (bf16_t*)(ws + (size_t)14 * 1048576);   // [14,16M)
  bf16_t* qkv    = (bf16_t*)(ws + (size_t)16 * 1048576);   // [16,40M)
  bf16_t* Mb     = (bf16_t*)(ws);                          // [0,0.5M) after gemm1
  bf16_t* Wt     = (bf16_t*)(ws + (size_t)1  * 1048576);   // [1,5M)   after gemm1
  float*  bqp    = (float*)d_out;                          // [0,12K)  until gemm1 done
  float*  Mpart  = (float*)d_out;                          // [0,16M)  after gemm1

  const float* bo = (const float*)d_in[ibo];

  conv_all_kernel <<<dim3(8195),   blk, 0, stream>>>((const float*)d_in[ix],
                                                     (const float*)d_in[iwq],
                                                     (const float*)d_in[iwo],
                                                     (const float*)d_in[ibq],
                                                     xb, wqkvb, wob, bqp);
  gemm1_256_kernel<<<dim3(12, 16), dim3(512), 0, stream>>>(xb, wqkvb, bqp, qkv);
  kv_part         <<<dim3(32, 16), blk, 0, stream>>>(qkv, Mpart);
  reduce_m        <<<dim3(8, 16),  blk, 0, stream>>>(Mpart, Mb);
  wprime_kernel   <<<dim3(8, 16),  blk, 0, stream>>>(wob, Mb, Wt);
  mfma_gemm_kernel<<<dim3(8, 32),  blk, 0, stream>>>(qkv, 3072, Wt, 1024, 1048576,
                                                     bo, nullptr, out, 1024, 1);
}

// Round 3
// 173.924 us; speedup vs baseline: 1.0706x; 1.0706x over previous
//
#include <hip/hip_runtime.h>
#include <hip/hip_bf16.h>
#include <stdint.h>

// B=2, N=2048, D=1024, H=8, DH=128. Inputs fp32, OUTPUT fp32.
// qkv col (reference) = kk*1024 + dd*8 + hh (head innermost). No softmax =>
//   out = sum_h Q_h (K_h^T V_h) Wo_h^T + b_o.
// v4 pipeline (6 kernels, all distinctly named for rocprof):
//   conv_all: x->bf16; w_qkv rows PERMUTED so gemm1 emits cols [kk][hh][dd];
//             w_o->bf16; b_qkv permuted (fp32).
//   gemm1:    m97 128^2 MFMA GEMM. qkv[4096][3072] bf16 (+bias). 768 blk = 3/CU.
//   kv_part:  Mpart[bh][ch][e][d] += K[n][e]*V[n][d]. 128-thr blocks, 8x8/thr
//             (VALU-bound), 512 blk = 2/CU.
//   reduce_m: M[bh][e][d] bf16 = sum_ch Mpart. 256 blk.
//   wprime:   Wt_b[o][h*128+e] = sum_d wo[o][h*128+d]*M[bh][e][d]. 128x64 tile,
//             K=128, 256 blk.
//   gemm2:    out[bn][o] = sum_he qkv[bn][he]*Wt_b[o][he] + b_o. 128x64 tile,
//             512 blk = 2/CU (was 256 = 1/CU, barrier-drain exposed).
// ws map (40 MB):
//   [0,8M)    xb      -> Mb [0,0.5M) + Wt [1M,5M)   (after gemm1)
//   [8,14M)   wqkvb   (dead after gemm1)
//   [14,16M)  wob     (live through wprime)
//   [16,40M)  qkv     (live through gemm2)
// d_out (16MB): bqp [0,12K) during gemm1; Mpart [0,16M) after gemm1;
//   overwritten by gemm2's final output.

typedef __bf16 bf16_t;
typedef __bf16 bf16x4 __attribute__((ext_vector_type(4)));
typedef __bf16 bf16x8 __attribute__((ext_vector_type(8)));
typedef float  fx4    __attribute__((ext_vector_type(4)));
typedef unsigned short u16;
typedef u16 u16x4 __attribute__((ext_vector_type(4)));
typedef u16 u16x8 __attribute__((ext_vector_type(8)));

typedef const void __attribute__((address_space(1)))* gas_ptr;
typedef void __attribute__((address_space(3)))*       las_ptr;

__device__ __forceinline__ void gl_lds16(const void* g, void* l) {
  __builtin_amdgcn_global_load_lds((gas_ptr)g, (las_ptr)l, 16, 0, 0);
}

// ---------------------------------------------------------------------------
__global__ __launch_bounds__(256) void beacon_kernel(float* out, float val, int n)
{
  const int i = blockIdx.x * 256 + threadIdx.x;
  if (i < n) out[i] = val;
}

// ---------------------------------------------------------------------------
__global__ __launch_bounds__(256) void conv_all_kernel(
    const float* __restrict__ x, const float* __restrict__ wq,
    const float* __restrict__ wo, const float* __restrict__ bq,
    bf16_t* __restrict__ xb, bf16_t* __restrict__ wqkvb,
    bf16_t* __restrict__ wob, float* __restrict__ bqp)
{
  const int i = blockIdx.x * 256 + threadIdx.x;   // < 2097920
  if (i < 2097152) {
    const float* src; bf16_t* dst; int soff, doff;
    if (i < 1048576) { src = x; dst = xb; soff = i; doff = i; }
    else if (i < 1835008) {
      const int j  = i - 1048576;
      const int rp = j >> 8, g = j & 255;       // dst row c' (0..3071), float4 group
      const int kk = rp >> 10, rem = rp & 1023;
      const int hh = rem >> 7,  dd = rem & 127;
      const int r  = kk * 1024 + dd * 8 + hh;   // src row c
      src = wq; dst = wqkvb; soff = r * 256 + g; doff = j;
    } else {
      const int j = i - 1835008;
      src = wo; dst = wob; soff = j; doff = j;
    }
    const float4 v = ((const float4*)src)[soff];
    bf16x4 o;
    o[0] = (bf16_t)v.x; o[1] = (bf16_t)v.y; o[2] = (bf16_t)v.z; o[3] = (bf16_t)v.w;
    ((bf16x4*)dst)[doff] = o;
  } else if (i < 2097920) {
    const int j = i - 2097152;                  // 0..767
    float4 v;
    float* pv = (float*)&v;
#pragma unroll
    for (int q = 0; q < 4; ++q) {
      const int cp = j * 4 + q;
      const int kk = cp >> 10, rem = cp & 1023;
      const int hh = rem >> 7,  dd = rem & 127;
      pv[q] = bq[kk * 1024 + dd * 8 + hh];
    }
    ((float4*)bqp)[j] = v;
  }
}

// ---------------------------------------------------------------------------
// gemm1: m97 structure, 128x128 tile, K=1024.
// qkv[4096][3072] = xb[4096][1024] @ wqkvb[3072][1024]^T + bqp (bf16 out).
__global__ __launch_bounds__(256) void gemm1_kernel(
    const bf16_t* __restrict__ A, const bf16_t* __restrict__ Bt,
    const float* __restrict__ bias, bf16_t* __restrict__ outb)
{
  __shared__ __align__(16) short As[128*32];
  __shared__ __align__(16) short Bs[128*32];
  const int t    = threadIdx.x;
  const int lane = t & 63;
  const int w    = t >> 6;
  const int wr   = (w >> 1) << 6;
  const int wc   = (w & 1) << 6;
  const int lrow = lane & 15;
  const int kq   = (lane >> 4) << 3;
  const int row0 = blockIdx.y * 128;
  const int col0 = blockIdx.x * 128;

  const int i0 = t, i1 = t + 256;
  const bf16_t* a0 = A  + (size_t)(row0 + (i0 >> 2)) * 1024 + ((i0 & 3) << 3);
  const bf16_t* a1 = A  + (size_t)(row0 + (i1 >> 2)) * 1024 + ((i1 & 3) << 3);
  const bf16_t* b0 = Bt + (size_t)(col0 + (i0 >> 2)) * 1024 + ((i0 & 3) << 3);
  const bf16_t* b1 = Bt + (size_t)(col0 + (i1 >> 2)) * 1024 + ((i1 & 3) << 3);
  short* sa0 = &As[i0 * 8]; short* sa1 = &As[i1 * 8];
  short* sb0 = &Bs[i0 * 8]; short* sb1 = &Bs[i1 * 8];

  fx4 acc[4][4] = {};

  for (int k0 = 0; k0 < 1024; k0 += 32) {
    gl_lds16(a0 + k0, sa0);
    gl_lds16(a1 + k0, sa1);
    gl_lds16(b0 + k0, sb0);
    gl_lds16(b1 + k0, sb1);
    __syncthreads();
    bf16x8 af[4], bfr[4];
#pragma unroll
    for (int i = 0; i < 4; ++i)
      af[i] = *(const bf16x8*)&As[(wr + i*16 + lrow)*32 + kq];
#pragma unroll
    for (int j = 0; j < 4; ++j)
      bfr[j] = *(const bf16x8*)&Bs[(wc + j*16 + lrow)*32 + kq];
#pragma unroll
    for (int i = 0; i < 4; ++i)
#pragma unroll
      for (int j = 0; j < 4; ++j)
        acc[i][j] = __builtin_amdgcn_mfma_f32_16x16x32_bf16(af[i], bfr[j], acc[i][j], 0, 0, 0);
    __syncthreads();
  }

#pragma unroll
  for (int j = 0; j < 4; ++j) {
    const int col = col0 + wc + j*16 + lrow;
    const float bv = bias[col];
#pragma unroll
    for (int i = 0; i < 4; ++i) {
#pragma unroll
      for (int r = 0; r < 4; ++r) {
        const int row = row0 + wr + i*16 + ((lane >> 4) << 2) + r;
        outb[(size_t)row * 3072 + col] = (bf16_t)(acc[i][j][r] + bv);
      }
    }
  }
}

// ---------------------------------------------------------------------------
// gemm2: 128x64 tile, K=1024. out[4096][1024] fp32 = qkv_Q @ Wt_b^T + bo.
// grid (16 colblk, 32 rowblk) = 512 blocks = 2/CU (vs 1/CU at 128x128).
__global__ __launch_bounds__(256) void gemm2_kernel(
    const bf16_t* __restrict__ A,      // qkv, lda=3072, Q cols at offset 0
    const bf16_t* __restrict__ Wt,     // [2][1024][1024], per-batch
    const float* __restrict__ bias,
    float* __restrict__ out)
{
  __shared__ __align__(16) short As[128*32];   // 8 KB
  __shared__ __align__(16) short Bs[64*32];    // 4 KB
  const int t    = threadIdx.x;
  const int lane = t & 63;
  const int w    = t >> 6;
  const int wm   = w >> 1;            // row-half (64)
  const int wn   = w & 1;             // col-half (32)
  const int lrow = lane & 15;
  const int kq   = (lane >> 4) << 3;
  const int row0 = blockIdx.y * 128;
  const int col0 = blockIdx.x * 64;
  const bf16_t* Bt = Wt + (row0 >= 2048 ? (size_t)1048576 : (size_t)0);

  const int i0 = t, i1 = t + 256;
  const bf16_t* a0 = A  + (size_t)(row0 + (i0 >> 2)) * 3072 + ((i0 & 3) << 3);
  const bf16_t* a1 = A  + (size_t)(row0 + (i1 >> 2)) * 3072 + ((i1 & 3) << 3);
  const bf16_t* b0 = Bt + (size_t)(col0 + (i0 >> 2)) * 1024 + ((i0 & 3) << 3);
  short* sa0 = &As[i0 * 8]; short* sa1 = &As[i1 * 8];
  short* sb0 = &Bs[i0 * 8];

  fx4 acc[4][2] = {};

  for (int k0 = 0; k0 < 1024; k0 += 32) {
    gl_lds16(a0 + k0, sa0);
    gl_lds16(a1 + k0, sa1);
    gl_lds16(b0 + k0, sb0);
    __syncthreads();
    bf16x8 af[4], bfr[2];
#pragma unroll
    for (int i = 0; i < 4; ++i)
      af[i] = *(const bf16x8*)&As[(wm*64 + i*16 + lrow)*32 + kq];
#pragma unroll
    for (int j = 0; j < 2; ++j)
      bfr[j] = *(const bf16x8*)&Bs[(wn*32 + j*16 + lrow)*32 + kq];
#pragma unroll
    for (int i = 0; i < 4; ++i)
#pragma unroll
      for (int j = 0; j < 2; ++j)
        acc[i][j] = __builtin_amdgcn_mfma_f32_16x16x32_bf16(af[i], bfr[j], acc[i][j], 0, 0, 0);
    __syncthreads();
  }

#pragma unroll
  for (int j = 0; j < 2; ++j) {
    const int col = col0 + wn*32 + j*16 + lrow;
    const float bv = bias[col];
#pragma unroll
    for (int i = 0; i < 4; ++i) {
#pragma unroll
      for (int r = 0; r < 4; ++r) {
        const int row = row0 + wm*64 + i*16 + ((lane >> 4) << 2) + r;
        out[(size_t)row * 1024 + col] = acc[i][j][r] + bv;
      }
    }
  }
}

// ---------------------------------------------------------------------------
// kv_part v3: Mpart[bh][ch][e][d] += K[n][e]*V[n][d] over n in 128-chunk.
// 128 threads/block, 8e x 8d per thread (64B LDS per 64 MACs -> VALU-bound).
// grid (32 = 16 ch x 2 dhalf, 16 bh) = 512 blocks, 48 KB LDS = 2/CU.
__global__ __launch_bounds__(128) void kv_part(
    const bf16_t* __restrict__ qkv, float* __restrict__ Mpart)
{
  __shared__ float Ksf[64][128];   // 32 KB
  __shared__ float Vsf[64][64];    // 16 KB
  const int t = threadIdx.x;       // 0..127
  const int ch = blockIdx.x >> 1, dh = blockIdx.x & 1, bh = blockIdx.y;
  const int b = bh >> 3, h = bh & 7;
  const bf16_t* Kg = qkv + (size_t)(b * 2048) * 3072 + 1024 + h * 128;
  const bf16_t* Vg = qkv + (size_t)(b * 2048) * 3072 + 2048 + h * 128 + dh * 64;
  const int e0 = (t >> 3) * 8;     // 16 groups x 8e = 128
  const int d0 = (t & 7) * 8;      // 8 groups x 8d = 64
  float acc[8][8] = {};

  for (int sub = 0; sub < 2; ++sub) {
    const int n0 = ch * 128 + sub * 64;
#pragma unroll
    for (int p = 0; p < 8; ++p) {           // K: 64 rows x 16 groups = 1024 tasks
      const int idx = t + p * 128;
      const int r = idx >> 4, c = (idx & 15) * 8;
      const bf16x8 k8 = *(const bf16x8*)(Kg + (size_t)(n0 + r) * 3072 + c);
      float4 f0 = { (float)k8[0], (float)k8[1], (float)k8[2], (float)k8[3] };
      float4 f1 = { (float)k8[4], (float)k8[5], (float)k8[6], (float)k8[7] };
      *(float4*)&Ksf[r][c]     = f0;
      *(float4*)&Ksf[r][c + 4] = f1;
    }
#pragma unroll
    for (int p = 0; p < 4; ++p) {           // V: 64 rows x 8 groups = 512 tasks
      const int idx = t + p * 128;
      const int r = idx >> 3, c = (idx & 7) * 8;
      const bf16x8 v8 = *(const bf16x8*)(Vg + (size_t)(n0 + r) * 3072 + c);
      float4 f0 = { (float)v8[0], (float)v8[1], (float)v8[2], (float)v8[3] };
      float4 f1 = { (float)v8[4], (float)v8[5], (float)v8[6], (float)v8[7] };
      *(float4*)&Vsf[r][c]     = f0;
      *(float4*)&Vsf[r][c + 4] = f1;
    }
    __syncthreads();
    for (int n = 0; n < 64; ++n) {
      const float4 ka = *(const float4*)&Ksf[n][e0];
      const float4 kb = *(const float4*)&Ksf[n][e0 + 4];
      const float4 va = *(const float4*)&Vsf[n][d0];
      const float4 vb = *(const float4*)&Vsf[n][d0 + 4];
      const float kf[8] = { ka.x, ka.y, ka.z, ka.w, kb.x, kb.y, kb.z, kb.w };
      const float vf[8] = { va.x, va.y, va.z, va.w, vb.x, vb.y, vb.z, vb.w };
#pragma unroll
      for (int i = 0; i < 8; ++i)
#pragma unroll
        for (int j = 0; j < 8; ++j) acc[i][j] += kf[i] * vf[j];
    }
    __syncthreads();
  }

  float* op = Mpart + ((size_t)(bh * 16 + ch) << 14) + dh * 64;
#pragma unroll
  for (int i = 0; i < 8; ++i) {
    *(float4*)&op[(e0 + i) * 128 + d0]     = *(const float4*)&acc[i][0];
    *(float4*)&op[(e0 + i) * 128 + d0 + 4] = *(const float4*)&acc[i][4];
  }
}

// ---------------------------------------------------------------------------
// reduce_m: M[bh][e][d] (bf16, row-major) = sum_{ch<16} Mpart[bh][ch][e][d]
// grid (16, 16) = 256 blocks (full chip); float4 tasks.
__global__ __launch_bounds__(256) void reduce_m(
    const float* __restrict__ Mpart, bf16_t* __restrict__ Mb)
{
  const int t = threadIdx.x, bh = blockIdx.y;
  const int task = blockIdx.x * 256 + t;    // 0..4095
  const int e = task >> 5, dq = task & 31;
  const float* base = Mpart + ((size_t)(bh * 16) << 14) + e * 128 + dq * 4;
  float4 s = { 0.f, 0.f, 0.f, 0.f };
#pragma unroll
  for (int ch = 0; ch < 16; ++ch) {
    const float4 v = *(const float4*)(base + ((size_t)ch << 14));
    s.x += v.x; s.y += v.y; s.z += v.z; s.w += v.w;
  }
  u16x4 wv;
  bf16_t b0 = (bf16_t)s.x; wv[0] = *(u16*)&b0;
  bf16_t b1 = (bf16_t)s.y; wv[1] = *(u16*)&b1;
  bf16_t b2 = (bf16_t)s.z; wv[2] = *(u16*)&b2;
  bf16_t b3 = (bf16_t)s.w; wv[3] = *(u16*)&b3;
  *(u16x4*)(Mb + (size_t)bh * 16384 + e * 128 + dq * 4) = wv;
}

// ---------------------------------------------------------------------------
// wprime: Wt_b[o][h*128+e] = sum_d wob[o][h*128+d] * M[bh][e][d].  K=128.
// 128x64 tile: grid (16 = 8 otile x 2 ehalf, 16 bh) = 256 blocks (was 128).
__global__ __launch_bounds__(256) void wprime_kernel(
    const bf16_t* __restrict__ wob, const bf16_t* __restrict__ Mb,
    bf16_t* __restrict__ Wt)
{
  __shared__ __align__(16) short As[128*32];
  __shared__ __align__(16) short Bs[64*32];
  const int t    = threadIdx.x;
  const int lane = t & 63;
  const int w    = t >> 6;
  const int wm   = w >> 1;
  const int wn   = w & 1;
  const int lrow = lane & 15;
  const int kq   = (lane >> 4) << 3;
  const int o0   = (blockIdx.x >> 1) * 128;
  const int eh   = (blockIdx.x & 1) * 64;
  const int bh   = blockIdx.y, b = bh >> 3, h = bh & 7;
  const bf16_t* A  = wob + (size_t)o0 * 1024 + h * 128;
  const bf16_t* Bt = Mb + (size_t)bh * 16384 + (size_t)eh * 128;

  const int i0 = t, i1 = t + 256;
  const bf16_t* a0 = A  + (size_t)(i0 >> 2) * 1024 + ((i0 & 3) << 3);
  const bf16_t* a1 = A  + (size_t)(i1 >> 2) * 1024 + ((i1 & 3) << 3);
  const bf16_t* b0 = Bt + (size_t)(i0 >> 2) * 128  + ((i0 & 3) << 3);
  short* sa0 = &As[i0 * 8]; short* sa1 = &As[i1 * 8];
  short* sb0 = &Bs[i0 * 8];

  fx4 acc[4][2] = {};

  for (int k0 = 0; k0 < 128; k0 += 32) {
    gl_lds16(a0 + k0, sa0);
    gl_lds16(a1 + k0, sa1);
    gl_lds16(b0 + k0, sb0);
    __syncthreads();
    bf16x8 af[4], bfr[2];
#pragma unroll
    for (int i = 0; i < 4; ++i)
      af[i] = *(const bf16x8*)&As[(wm*64 + i*16 + lrow)*32 + kq];
#pragma unroll
    for (int j = 0; j < 2; ++j)
      bfr[j] = *(const bf16x8*)&Bs[(wn*32 + j*16 + lrow)*32 + kq];
#pragma unroll
    for (int i = 0; i < 4; ++i)
#pragma unroll
      for (int j = 0; j < 2; ++j)
        acc[i][j] = __builtin_amdgcn_mfma_f32_16x16x32_bf16(af[i], bfr[j], acc[i][j], 0, 0, 0);
    __syncthreads();
  }

  bf16_t* obase = Wt + (size_t)b * 1048576 + h * 128;
#pragma unroll
  for (int j = 0; j < 2; ++j) {
    const int col = eh + wn*32 + j*16 + lrow;         // e 0..127
#pragma unroll
    for (int i = 0; i < 4; ++i) {
#pragma unroll
      for (int r = 0; r < 4; ++r) {
        const int row = o0 + wm*64 + i*16 + ((lane >> 4) << 2) + r;   // o
        obase[(size_t)row * 1024 + col] = (bf16_t)acc[i][j][r];
      }
    }
  }
}

// ---------------------------------------------------------------------------
extern "C" void kernel_launch(void* const* d_in, const int* in_sizes, int n_in,
                              void* d_out, int out_size, void* d_ws, size_t ws_size,
                              hipStream_t stream) {
  float* out = (float*)d_out;
  dim3 blk(256);

  int ix = -1, iwq = -1, ibq = -1, iwo = -1, ibo = -1;
  if (n_in == 5) {
    for (int i = 0; i < 5; ++i) {
      switch (in_sizes[i]) {
        case 4194304: ix  = i; break;
        case 3145728: iwq = i; break;
        case 3072:    ibq = i; break;
        case 1048576: iwo = i; break;
        case 1024:    ibo = i; break;
        default: break;
      }
    }
  }
  if (ix < 0 || iwq < 0 || ibq < 0 || iwo < 0 || ibo < 0) {
    beacon_kernel<<<dim3((out_size + 255) / 256), blk, 0, stream>>>(out, 50000.0f, out_size);
    return;
  }
  const size_t NEEDED = (size_t)40 * 1048576;
  if (ws_size < NEEDED) {
    beacon_kernel<<<dim3((out_size + 255) / 256), blk, 0, stream>>>(out, 30000.0f, out_size);
    return;
  }

  char* ws = (char*)d_ws;
  bf16_t* xb     = (bf16_t*)(ws);                          // [0,8M)
  bf16_t* wqkvb  = (bf16_t*)(ws + (size_t)8  * 1048576);   // [8,14M)
  bf16_t* wob    = (bf16_t*)(ws + (size_t)14 * 1048576);   // [14,16M)
  bf16_t* qkv    = (bf16_t*)(ws + (size_t)16 * 1048576);   // [16,40M)
  bf16_t* Mb     = (bf16_t*)(ws);                          // [0,0.5M) after gemm1
  bf16_t* Wt     = (bf16_t*)(ws + (size_t)1  * 1048576);   // [1,5M)   after gemm1
  float*  bqp    = (float*)d_out;                          // [0,12K)  until gemm1 done
  float*  Mpart  = (float*)d_out;                          // [0,16M)  after gemm1

  const float* bo = (const float*)d_in[ibo];

  conv_all_kernel<<<dim3(8195),   blk, 0, stream>>>((const float*)d_in[ix],
                                                    (const float*)d_in[iwq],
                                                    (const float*)d_in[iwo],
                                                    (const float*)d_in[ibq],
                                                    xb, wqkvb, wob, bqp);
  gemm1_kernel   <<<dim3(24, 32), blk, 0, stream>>>(xb, wqkvb, bqp, qkv);
  kv_part        <<<dim3(32, 16), dim3(128), 0, stream>>>(qkv, Mpart);
  reduce_m       <<<dim3(16, 16), blk, 0, stream>>>(Mpart, Mb);
  wprime_kernel  <<<dim3(16, 16), blk, 0, stream>>>(wob, Mb, Wt);
  gemm2_kernel   <<<dim3(16, 32), blk, 0, stream>>>(qkv, Wt, bo, out);
}

// Round 4
// 166.567 us; speedup vs baseline: 1.1179x; 1.0442x over previous
//
#include <hip/hip_runtime.h>
#include <hip/hip_bf16.h>
#include <stdint.h>

// B=2, N=2048, D=1024, H=8, DH=128. Inputs fp32, OUTPUT fp32.
// qkv col (reference) = kk*1024 + dd*8 + hh (head innermost). No softmax =>
//   out = sum_h Q_h (K_h^T V_h) Wo_h^T + b_o.
// v5 pipeline (7 kernels):
//   conv_all: x->bf16; w_qkv rows PERMUTED so gemm1 emits cols [kk][hh][dd];
//             w_o->bf16; b_qkv permuted (fp32).
//   gemm1:    m97 128^2, BK=64 (two buffer pairs, half the barriers).
//             qkv[4096][3072] bf16 (+bias). 768 blk = 3/CU.
//   kt_vt:    LDS transpose: Kt[bh][e][n], Vt[bh][d][n] bf16 (MFMA-ready).
//   kvt_mfma: Mpart2[bh][ks][e][d] fp32 = Kt[e][ks-chunk] @ Vt[d][ks-chunk]^T
//             (MFMA, K-split 8x256). 128 blocks.
//   reduce_m2: Mb[bh][e][d] bf16 = sum_ks Mpart2. 256 blk.
//   wprime:   Wt_b[o][h*128+e] = sum_d wo[o][h*128+d]*M[bh][e][d]. 128x64, 256 blk.
//   gemm2:    out[bn][o] = sum_he qkv[bn][he]*Wt_b[o][he] + b_o. 128x64, BK=64,
//             512 blk = 2/CU.
// ws map (40 MB):
//   [0,8M)    xb     -> Kt (after gemm1)
//   [8,14M)   wqkvb  -> Mb [8,8.5M) + Wt [9,13M) (after gemm1)
//   [14,16M)  wob    (live through wprime)
//   [16,40M)  qkv    (live through gemm2)
// d_out (16MB): bqp [0,12K) during gemm1; Vt [8,16M) + Mpart2 [0,8M) after;
//   overwritten by gemm2's final output (Vt dead after kvt_mfma, Mpart2 after
//   reduce_m2).

typedef __bf16 bf16_t;
typedef __bf16 bf16x4 __attribute__((ext_vector_type(4)));
typedef __bf16 bf16x8 __attribute__((ext_vector_type(8)));
typedef float  fx4    __attribute__((ext_vector_type(4)));
typedef unsigned short u16;
typedef u16 u16x4 __attribute__((ext_vector_type(4)));
typedef u16 u16x8 __attribute__((ext_vector_type(8)));

typedef const void __attribute__((address_space(1)))* gas_ptr;
typedef void __attribute__((address_space(3)))*       las_ptr;

__device__ __forceinline__ void gl_lds16(const void* g, void* l) {
  __builtin_amdgcn_global_load_lds((gas_ptr)g, (las_ptr)l, 16, 0, 0);
}

#define TSLAB 262144   // 128*2048 elems per (b,h) transposed slab

// ---------------------------------------------------------------------------
__global__ __launch_bounds__(256) void beacon_kernel(float* out, float val, int n)
{
  const int i = blockIdx.x * 256 + threadIdx.x;
  if (i < n) out[i] = val;
}

// ---------------------------------------------------------------------------
__global__ __launch_bounds__(256) void conv_all_kernel(
    const float* __restrict__ x, const float* __restrict__ wq,
    const float* __restrict__ wo, const float* __restrict__ bq,
    bf16_t* __restrict__ xb, bf16_t* __restrict__ wqkvb,
    bf16_t* __restrict__ wob, float* __restrict__ bqp)
{
  const int i = blockIdx.x * 256 + threadIdx.x;   // < 2097920
  if (i < 2097152) {
    const float* src; bf16_t* dst; int soff, doff;
    if (i < 1048576) { src = x; dst = xb; soff = i; doff = i; }
    else if (i < 1835008) {
      const int j  = i - 1048576;
      const int rp = j >> 8, g = j & 255;       // dst row c' (0..3071), float4 group
      const int kk = rp >> 10, rem = rp & 1023;
      const int hh = rem >> 7,  dd = rem & 127;
      const int r  = kk * 1024 + dd * 8 + hh;   // src row c
      src = wq; dst = wqkvb; soff = r * 256 + g; doff = j;
    } else {
      const int j = i - 1835008;
      src = wo; dst = wob; soff = j; doff = j;
    }
    const float4 v = ((const float4*)src)[soff];
    bf16x4 o;
    o[0] = (bf16_t)v.x; o[1] = (bf16_t)v.y; o[2] = (bf16_t)v.z; o[3] = (bf16_t)v.w;
    ((bf16x4*)dst)[doff] = o;
  } else if (i < 2097920) {
    const int j = i - 2097152;                  // 0..767
    float4 v;
    float* pv = (float*)&v;
#pragma unroll
    for (int q = 0; q < 4; ++q) {
      const int cp = j * 4 + q;
      const int kk = cp >> 10, rem = cp & 1023;
      const int hh = rem >> 7,  dd = rem & 127;
      pv[q] = bq[kk * 1024 + dd * 8 + hh];
    }
    ((float4*)bqp)[j] = v;
  }
}

// ---------------------------------------------------------------------------
// gemm1: 128x128 tile, BK=64 via two independent buffer pairs (one sync pair
// per 64-k instead of per 32-k). qkv = xb @ wqkvb^T + bqp (bf16 out, ldc 3072).
__global__ __launch_bounds__(256) void gemm1_kernel(
    const bf16_t* __restrict__ A, const bf16_t* __restrict__ Bt,
    const float* __restrict__ bias, bf16_t* __restrict__ outb)
{
  __shared__ __align__(16) short As0[128*32], As1[128*32];
  __shared__ __align__(16) short Bs0[128*32], Bs1[128*32];
  const int t    = threadIdx.x;
  const int lane = t & 63;
  const int w    = t >> 6;
  const int wr   = (w >> 1) << 6;
  const int wc   = (w & 1) << 6;
  const int lrow = lane & 15;
  const int kq   = (lane >> 4) << 3;
  const int row0 = blockIdx.y * 128;
  const int col0 = blockIdx.x * 128;

  const int i0 = t, i1 = t + 256;
  const bf16_t* a0 = A  + (size_t)(row0 + (i0 >> 2)) * 1024 + ((i0 & 3) << 3);
  const bf16_t* a1 = A  + (size_t)(row0 + (i1 >> 2)) * 1024 + ((i1 & 3) << 3);
  const bf16_t* b0 = Bt + (size_t)(col0 + (i0 >> 2)) * 1024 + ((i0 & 3) << 3);
  const bf16_t* b1 = Bt + (size_t)(col0 + (i1 >> 2)) * 1024 + ((i1 & 3) << 3);

  fx4 acc[4][4] = {};

  for (int k0 = 0; k0 < 1024; k0 += 64) {
    gl_lds16(a0 + k0,      &As0[i0 * 8]);
    gl_lds16(a1 + k0,      &As0[i1 * 8]);
    gl_lds16(b0 + k0,      &Bs0[i0 * 8]);
    gl_lds16(b1 + k0,      &Bs0[i1 * 8]);
    gl_lds16(a0 + k0 + 32, &As1[i0 * 8]);
    gl_lds16(a1 + k0 + 32, &As1[i1 * 8]);
    gl_lds16(b0 + k0 + 32, &Bs1[i0 * 8]);
    gl_lds16(b1 + k0 + 32, &Bs1[i1 * 8]);
    __syncthreads();
    {
      bf16x8 af[4], bfr[4];
#pragma unroll
      for (int i = 0; i < 4; ++i)
        af[i] = *(const bf16x8*)&As0[(wr + i*16 + lrow)*32 + kq];
#pragma unroll
      for (int j = 0; j < 4; ++j)
        bfr[j] = *(const bf16x8*)&Bs0[(wc + j*16 + lrow)*32 + kq];
#pragma unroll
      for (int i = 0; i < 4; ++i)
#pragma unroll
        for (int j = 0; j < 4; ++j)
          acc[i][j] = __builtin_amdgcn_mfma_f32_16x16x32_bf16(af[i], bfr[j], acc[i][j], 0, 0, 0);
    }
    {
      bf16x8 af[4], bfr[4];
#pragma unroll
      for (int i = 0; i < 4; ++i)
        af[i] = *(const bf16x8*)&As1[(wr + i*16 + lrow)*32 + kq];
#pragma unroll
      for (int j = 0; j < 4; ++j)
        bfr[j] = *(const bf16x8*)&Bs1[(wc + j*16 + lrow)*32 + kq];
#pragma unroll
      for (int i = 0; i < 4; ++i)
#pragma unroll
        for (int j = 0; j < 4; ++j)
          acc[i][j] = __builtin_amdgcn_mfma_f32_16x16x32_bf16(af[i], bfr[j], acc[i][j], 0, 0, 0);
    }
    __syncthreads();
  }

#pragma unroll
  for (int j = 0; j < 4; ++j) {
    const int col = col0 + wc + j*16 + lrow;
    const float bv = bias[col];
#pragma unroll
    for (int i = 0; i < 4; ++i) {
#pragma unroll
      for (int r = 0; r < 4; ++r) {
        const int row = row0 + wr + i*16 + ((lane >> 4) << 2) + r;
        outb[(size_t)row * 3072 + col] = (bf16_t)(acc[i][j][r] + bv);
      }
    }
  }
}

// ---------------------------------------------------------------------------
// kt_vt: transpose K and V head-slices out of qkv into MFMA-ready layouts:
//   Kt[bh][e][n] = qkv[b*2048+n][1024 + h*128 + e]
//   Vt[bh][d][n] = qkv[b*2048+n][2048 + h*128 + d]
// grid (32 ntiles, 32 = bh*2+kv). Block 256. LDS 64x132 u16 (padded).
__global__ __launch_bounds__(256) void kt_vt_kernel(
    const bf16_t* __restrict__ qkv, bf16_t* __restrict__ Kt,
    bf16_t* __restrict__ Vt)
{
  __shared__ u16 L[64][132];
  const int t  = threadIdx.x;
  const int n0 = blockIdx.x * 64;
  const int bh = blockIdx.y >> 1, kv = blockIdx.y & 1;
  const int b  = bh >> 3, h = bh & 7;
  const u16* src = (const u16*)qkv + (size_t)(b * 2048 + n0) * 3072
                   + (1 + kv) * 1024 + h * 128;

#pragma unroll
  for (int p = 0; p < 4; ++p) {             // read 64 rows x 16 groups
    const int idx = t + p * 256;
    const int r = idx >> 4, g = idx & 15;
    const u16x8 v = *(const u16x8*)(src + (size_t)r * 3072 + 8 * g);
    *(u16x8*)&L[r][8 * g] = v;
  }
  __syncthreads();

  bf16_t* dstb = (kv == 0 ? Kt : Vt) + (size_t)bh * TSLAB;
#pragma unroll
  for (int p = 0; p < 4; ++p) {             // write 128 c-rows x 8 n-groups
    const int idx = t + p * 256;
    const int c = idx >> 3, gn = idx & 7;
    u16x8 wv;
#pragma unroll
    for (int j = 0; j < 8; ++j) wv[j] = L[8 * gn + j][c];
    *(u16x8*)(dstb + (size_t)c * 2048 + n0 + 8 * gn) = wv;
  }
}

// ---------------------------------------------------------------------------
// kvt_mfma: Mpart2[bh][ks][e][d] = sum_{n in ks-chunk} Kt[bh][e][n]*Vt[bh][d][n]
// m97 A*Bt^T form, lda=ldb=2048, K-chunk 256 (8 iters of 32). grid (8 ks, 16 bh).
__global__ __launch_bounds__(256) void kvt_mfma_kernel(
    const bf16_t* __restrict__ Kt, const bf16_t* __restrict__ Vt,
    float* __restrict__ Mpart2)
{
  __shared__ __align__(16) short As[128*32];
  __shared__ __align__(16) short Bs[128*32];
  const int t    = threadIdx.x;
  const int lane = t & 63;
  const int w    = t >> 6;
  const int wr   = (w >> 1) << 6;
  const int wc   = (w & 1) << 6;
  const int lrow = lane & 15;
  const int kq   = (lane >> 4) << 3;
  const int ks   = blockIdx.x;        // 0..7, n-chunk of 256
  const int bh   = blockIdx.y;
  const bf16_t* Ab = Kt + (size_t)bh * TSLAB + ks * 256;
  const bf16_t* Bb = Vt + (size_t)bh * TSLAB + ks * 256;

  const int i0 = t, i1 = t + 256;
  const bf16_t* a0 = Ab + (size_t)(i0 >> 2) * 2048 + ((i0 & 3) << 3);
  const bf16_t* a1 = Ab + (size_t)(i1 >> 2) * 2048 + ((i1 & 3) << 3);
  const bf16_t* b0 = Bb + (size_t)(i0 >> 2) * 2048 + ((i0 & 3) << 3);
  const bf16_t* b1 = Bb + (size_t)(i1 >> 2) * 2048 + ((i1 & 3) << 3);
  short* sa0 = &As[i0 * 8]; short* sa1 = &As[i1 * 8];
  short* sb0 = &Bs[i0 * 8]; short* sb1 = &Bs[i1 * 8];

  fx4 acc[4][4] = {};

  for (int k0 = 0; k0 < 256; k0 += 32) {
    gl_lds16(a0 + k0, sa0);
    gl_lds16(a1 + k0, sa1);
    gl_lds16(b0 + k0, sb0);
    gl_lds16(b1 + k0, sb1);
    __syncthreads();
    bf16x8 af[4], bfr[4];
#pragma unroll
    for (int i = 0; i < 4; ++i)
      af[i] = *(const bf16x8*)&As[(wr + i*16 + lrow)*32 + kq];
#pragma unroll
    for (int j = 0; j < 4; ++j)
      bfr[j] = *(const bf16x8*)&Bs[(wc + j*16 + lrow)*32 + kq];
#pragma unroll
    for (int i = 0; i < 4; ++i)
#pragma unroll
      for (int j = 0; j < 4; ++j)
        acc[i][j] = __builtin_amdgcn_mfma_f32_16x16x32_bf16(af[i], bfr[j], acc[i][j], 0, 0, 0);
    __syncthreads();
  }

  float* op = Mpart2 + ((size_t)(bh * 8 + ks) << 14);
#pragma unroll
  for (int j = 0; j < 4; ++j) {
    const int col = wc + j*16 + lrow;                 // d
#pragma unroll
    for (int i = 0; i < 4; ++i) {
#pragma unroll
      for (int r = 0; r < 4; ++r) {
        const int row = wr + i*16 + ((lane >> 4) << 2) + r;   // e
        op[(size_t)row * 128 + col] = acc[i][j][r];
      }
    }
  }
}

// ---------------------------------------------------------------------------
// reduce_m2: Mb[bh][e][d] bf16 = sum_{ks<8} Mpart2[bh][ks][e][d]. grid (16,16).
__global__ __launch_bounds__(256) void reduce_m2(
    const float* __restrict__ Mpart2, bf16_t* __restrict__ Mb)
{
  const int t = threadIdx.x, bh = blockIdx.y;
  const int task = blockIdx.x * 256 + t;    // 0..4095 float4 within bh slab
  const float* base = Mpart2 + ((size_t)(bh * 8) << 14) + task * 4;
  float4 s = { 0.f, 0.f, 0.f, 0.f };
#pragma unroll
  for (int ks = 0; ks < 8; ++ks) {
    const float4 v = *(const float4*)(base + ((size_t)ks << 14));
    s.x += v.x; s.y += v.y; s.z += v.z; s.w += v.w;
  }
  u16x4 wv;
  bf16_t b0 = (bf16_t)s.x; wv[0] = *(u16*)&b0;
  bf16_t b1 = (bf16_t)s.y; wv[1] = *(u16*)&b1;
  bf16_t b2 = (bf16_t)s.z; wv[2] = *(u16*)&b2;
  bf16_t b3 = (bf16_t)s.w; wv[3] = *(u16*)&b3;
  *(u16x4*)(Mb + (size_t)bh * 16384 + task * 4) = wv;
}

// ---------------------------------------------------------------------------
// wprime: Wt_b[o][h*128+e] = sum_d wob[o][h*128+d] * Mb[bh][e][d].  K=128.
// 128x64 tile: grid (16 = 8 otile x 2 ehalf, 16 bh) = 256 blocks.
__global__ __launch_bounds__(256) void wprime_kernel(
    const bf16_t* __restrict__ wob, const bf16_t* __restrict__ Mb,
    bf16_t* __restrict__ Wt)
{
  __shared__ __align__(16) short As[128*32];
  __shared__ __align__(16) short Bs[64*32];
  const int t    = threadIdx.x;
  const int lane = t & 63;
  const int w    = t >> 6;
  const int wm   = w >> 1;
  const int wn   = w & 1;
  const int lrow = lane & 15;
  const int kq   = (lane >> 4) << 3;
  const int o0   = (blockIdx.x >> 1) * 128;
  const int eh   = (blockIdx.x & 1) * 64;
  const int bh   = blockIdx.y, b = bh >> 3, h = bh & 7;
  const bf16_t* A  = wob + (size_t)o0 * 1024 + h * 128;
  const bf16_t* Bt = Mb + (size_t)bh * 16384 + (size_t)eh * 128;

  const int i0 = t, i1 = t + 256;
  const bf16_t* a0 = A  + (size_t)(i0 >> 2) * 1024 + ((i0 & 3) << 3);
  const bf16_t* a1 = A  + (size_t)(i1 >> 2) * 1024 + ((i1 & 3) << 3);
  const bf16_t* b0 = Bt + (size_t)(i0 >> 2) * 128  + ((i0 & 3) << 3);
  short* sa0 = &As[i0 * 8]; short* sa1 = &As[i1 * 8];
  short* sb0 = &Bs[i0 * 8];

  fx4 acc[4][2] = {};

  for (int k0 = 0; k0 < 128; k0 += 32) {
    gl_lds16(a0 + k0, sa0);
    gl_lds16(a1 + k0, sa1);
    gl_lds16(b0 + k0, sb0);
    __syncthreads();
    bf16x8 af[4], bfr[2];
#pragma unroll
    for (int i = 0; i < 4; ++i)
      af[i] = *(const bf16x8*)&As[(wm*64 + i*16 + lrow)*32 + kq];
#pragma unroll
    for (int j = 0; j < 2; ++j)
      bfr[j] = *(const bf16x8*)&Bs[(wn*32 + j*16 + lrow)*32 + kq];
#pragma unroll
    for (int i = 0; i < 4; ++i)
#pragma unroll
      for (int j = 0; j < 2; ++j)
        acc[i][j] = __builtin_amdgcn_mfma_f32_16x16x32_bf16(af[i], bfr[j], acc[i][j], 0, 0, 0);
    __syncthreads();
  }

  bf16_t* obase = Wt + (size_t)b * 1048576 + h * 128;
#pragma unroll
  for (int j = 0; j < 2; ++j) {
    const int col = eh + wn*32 + j*16 + lrow;         // e 0..127
#pragma unroll
    for (int i = 0; i < 4; ++i) {
#pragma unroll
      for (int r = 0; r < 4; ++r) {
        const int row = o0 + wm*64 + i*16 + ((lane >> 4) << 2) + r;   // o
        obase[(size_t)row * 1024 + col] = (bf16_t)acc[i][j][r];
      }
    }
  }
}

// ---------------------------------------------------------------------------
// gemm2: 128x64 tile, BK=64 (two buffer pairs). out fp32 = qkv_Q @ Wt_b^T + bo.
// grid (16 colblk, 32 rowblk) = 512 blocks = 2/CU.
__global__ __launch_bounds__(256) void gemm2_kernel(
    const bf16_t* __restrict__ A,      // qkv, lda=3072, Q cols at offset 0
    const bf16_t* __restrict__ Wt,     // [2][1024][1024], per-batch
    const float* __restrict__ bias,
    float* __restrict__ out)
{
  __shared__ __align__(16) short As0[128*32], As1[128*32];
  __shared__ __align__(16) short Bs0[64*32],  Bs1[64*32];
  const int t    = threadIdx.x;
  const int lane = t & 63;
  const int w    = t >> 6;
  const int wm   = w >> 1;            // row-half (64)
  const int wn   = w & 1;             // col-half (32)
  const int lrow = lane & 15;
  const int kq   = (lane >> 4) << 3;
  const int row0 = blockIdx.y * 128;
  const int col0 = blockIdx.x * 64;
  const bf16_t* Bt = Wt + (row0 >= 2048 ? (size_t)1048576 : (size_t)0);

  const int i0 = t, i1 = t + 256;
  const bf16_t* a0 = A  + (size_t)(row0 + (i0 >> 2)) * 3072 + ((i0 & 3) << 3);
  const bf16_t* a1 = A  + (size_t)(row0 + (i1 >> 2)) * 3072 + ((i1 & 3) << 3);
  const bf16_t* b0 = Bt + (size_t)(col0 + (i0 >> 2)) * 1024 + ((i0 & 3) << 3);

  fx4 acc[4][2] = {};

  for (int k0 = 0; k0 < 1024; k0 += 64) {
    gl_lds16(a0 + k0,      &As0[i0 * 8]);
    gl_lds16(a1 + k0,      &As0[i1 * 8]);
    gl_lds16(b0 + k0,      &Bs0[i0 * 8]);
    gl_lds16(a0 + k0 + 32, &As1[i0 * 8]);
    gl_lds16(a1 + k0 + 32, &As1[i1 * 8]);
    gl_lds16(b0 + k0 + 32, &Bs1[i0 * 8]);
    __syncthreads();
    {
      bf16x8 af[4], bfr[2];
#pragma unroll
      for (int i = 0; i < 4; ++i)
        af[i] = *(const bf16x8*)&As0[(wm*64 + i*16 + lrow)*32 + kq];
#pragma unroll
      for (int j = 0; j < 2; ++j)
        bfr[j] = *(const bf16x8*)&Bs0[(wn*32 + j*16 + lrow)*32 + kq];
#pragma unroll
      for (int i = 0; i < 4; ++i)
#pragma unroll
        for (int j = 0; j < 2; ++j)
          acc[i][j] = __builtin_amdgcn_mfma_f32_16x16x32_bf16(af[i], bfr[j], acc[i][j], 0, 0, 0);
    }
    {
      bf16x8 af[4], bfr[2];
#pragma unroll
      for (int i = 0; i < 4; ++i)
        af[i] = *(const bf16x8*)&As1[(wm*64 + i*16 + lrow)*32 + kq];
#pragma unroll
      for (int j = 0; j < 2; ++j)
        bfr[j] = *(const bf16x8*)&Bs1[(wn*32 + j*16 + lrow)*32 + kq];
#pragma unroll
      for (int i = 0; i < 4; ++i)
#pragma unroll
        for (int j = 0; j < 2; ++j)
          acc[i][j] = __builtin_amdgcn_mfma_f32_16x16x32_bf16(af[i], bfr[j], acc[i][j], 0, 0, 0);
    }
    __syncthreads();
  }

#pragma unroll
  for (int j = 0; j < 2; ++j) {
    const int col = col0 + wn*32 + j*16 + lrow;
    const float bv = bias[col];
#pragma unroll
    for (int i = 0; i < 4; ++i) {
#pragma unroll
      for (int r = 0; r < 4; ++r) {
        const int row = row0 + wm*64 + i*16 + ((lane >> 4) << 2) + r;
        out[(size_t)row * 1024 + col] = acc[i][j][r] + bv;
      }
    }
  }
}

// ---------------------------------------------------------------------------
extern "C" void kernel_launch(void* const* d_in, const int* in_sizes, int n_in,
                              void* d_out, int out_size, void* d_ws, size_t ws_size,
                              hipStream_t stream) {
  float* out = (float*)d_out;
  dim3 blk(256);

  int ix = -1, iwq = -1, ibq = -1, iwo = -1, ibo = -1;
  if (n_in == 5) {
    for (int i = 0; i < 5; ++i) {
      switch (in_sizes[i]) {
        case 4194304: ix  = i; break;
        case 3145728: iwq = i; break;
        case 3072:    ibq = i; break;
        case 1048576: iwo = i; break;
        case 1024:    ibo = i; break;
        default: break;
      }
    }
  }
  if (ix < 0 || iwq < 0 || ibq < 0 || iwo < 0 || ibo < 0) {
    beacon_kernel<<<dim3((out_size + 255) / 256), blk, 0, stream>>>(out, 50000.0f, out_size);
    return;
  }
  const size_t NEEDED = (size_t)40 * 1048576;
  if (ws_size < NEEDED) {
    beacon_kernel<<<dim3((out_size + 255) / 256), blk, 0, stream>>>(out, 30000.0f, out_size);
    return;
  }

  char* ws = (char*)d_ws;
  bf16_t* xb     = (bf16_t*)(ws);                          // [0,8M)
  bf16_t* wqkvb  = (bf16_t*)(ws + (size_t)8  * 1048576);   // [8,14M)
  bf16_t* wob    = (bf16_t*)(ws + (size_t)14 * 1048576);   // [14,16M)
  bf16_t* qkv    = (bf16_t*)(ws + (size_t)16 * 1048576);   // [16,40M)
  bf16_t* Kt     = (bf16_t*)(ws);                          // [0,8M)   after gemm1
  bf16_t* Mb     = (bf16_t*)(ws + (size_t)8  * 1048576);   // [8,8.5M) after gemm1
  bf16_t* Wt     = (bf16_t*)(ws + (size_t)9  * 1048576);   // [9,13M)  after gemm1
  float*  bqp    = (float*)d_out;                          // [0,12K)  until gemm1 done
  float*  Mpart2 = (float*)d_out;                          // [0,8M)   after gemm1
  bf16_t* Vt     = (bf16_t*)d_out + 4194304;               // [8,16M)  after gemm1

  const float* bo = (const float*)d_in[ibo];

  conv_all_kernel<<<dim3(8195),   blk, 0, stream>>>((const float*)d_in[ix],
                                                    (const float*)d_in[iwq],
                                                    (const float*)d_in[iwo],
                                                    (const float*)d_in[ibq],
                                                    xb, wqkvb, wob, bqp);
  gemm1_kernel   <<<dim3(24, 32), blk, 0, stream>>>(xb, wqkvb, bqp, qkv);
  kt_vt_kernel   <<<dim3(32, 32), blk, 0, stream>>>(qkv, Kt, Vt);
  kvt_mfma_kernel<<<dim3(8, 16),  blk, 0, stream>>>(Kt, Vt, Mpart2);
  reduce_m2      <<<dim3(16, 16), blk, 0, stream>>>(Mpart2, Mb);
  wprime_kernel  <<<dim3(16, 16), blk, 0, stream>>>(wob, Mb, Wt);
  gemm2_kernel   <<<dim3(16, 32), blk, 0, stream>>>(qkv, Wt, bo, out);
}